// Round 12
// baseline (204.363 us; speedup 1.0000x reference)
//
#include <hip/hip_runtime.h>

typedef unsigned int u32;
typedef unsigned long long u64;
typedef __bf16 bf16x8 __attribute__((ext_vector_type(8)));
typedef float f32x4 __attribute__((ext_vector_type(4)));

#define N_TOK 4096   // B*S
#define IN_DIM 2048
#define OUT_DIM 4096
#define NCB 128      // codebooks C
#define NCENT 16     // centroids K
#define VLEN 16      // vec_len V
#define CK 2048      // NCB*NCENT  (GEMM inner dim)
#define KB 64        // K-blocks (CK/32)

static __device__ __forceinline__ unsigned short f2bf(float f) {
  u32 u = __float_as_uint(f);
  u = (u + 0x7FFFu + ((u >> 16) & 1u)) >> 16;  // round-to-nearest-even
  return (unsigned short)u;
}

// ---------------------------------------------------------------------------
// k_prep: lut-build (blocks 0..1023) || Chebyshev argmin (blocks 1024..2047).
// Unchanged (passed R2-R11; not the bottleneck).
// ---------------------------------------------------------------------------
__global__ __launch_bounds__(256) void k_prep(
    const float* __restrict__ x,
    const float* __restrict__ w,
    const float* __restrict__ cents,
    unsigned char* __restrict__ idx,
    char* __restrict__ lutF) {
  __shared__ float cs[16 * 260];  // 16.6KB (argmin path only)
  const int tid = threadIdx.x;
  const int b = blockIdx.x;

  if (b < 1024) {
    // ---- LUT path ----
    const int o0 = (b & 63) * 64;
    const int cg = b >> 6;  // 8-codebook group 0..15
    const int p = tid >> 6;
    const int ol = tid & 63;
    const int o = o0 + ol;

    float acc[2][16];
#pragma unroll
    for (int cc = 0; cc < 2; ++cc)
#pragma unroll
      for (int k = 0; k < 16; ++k) acc[cc][k] = 0.f;

#pragma unroll
    for (int cc = 0; cc < 2; ++cc) {
      const int c = __builtin_amdgcn_readfirstlane(cg * 8 + p * 2 + cc);
      const float* cb = cents + (size_t)c * (NCENT * VLEN);  // scalar loads
#pragma unroll
      for (int v = 0; v < VLEN; ++v) {
        const float wv = w[(size_t)(c * 16 + v) * OUT_DIM + o];
#pragma unroll
        for (int k = 0; k < 16; ++k) acc[cc][k] = fmaf(cb[k * 16 + v], wv, acc[cc][k]);
      }
    }

#pragma unroll
    for (int cc = 0; cc < 2; ++cc) {
      const int c = cg * 8 + p * 2 + cc;
      u32 g[8];
#pragma unroll
      for (int kk = 0; kk < 8; ++kk)
        g[kk] = (u32)f2bf(acc[cc][2 * kk]) | ((u32)f2bf(acc[cc][2 * kk + 1]) << 16);
      char* base = lutF + ((size_t)(o >> 4) * KB + (c >> 1)) * 1024;
      const int l0 = (o & 15) + ((c & 1) * 2) * 16;
      *(uint4*)(base + l0 * 16)        = make_uint4(g[0], g[1], g[2], g[3]);
      *(uint4*)(base + (l0 + 16) * 16) = make_uint4(g[4], g[5], g[6], g[7]);
    }
    return;
  }

  // ---- argmin path ----
  const int a = b - 1024;
  const int n0 = (a & 127) * 32;
  const int cg = a >> 7;  // column chunk 0..7
  const int t = tid >> 4;
  const int cl = tid & 15;

#pragma unroll
  for (int j2 = 0; j2 < 4; ++j2) {
    const int fi = tid + 256 * j2;
    const int row = fi >> 6;
    const int col = (fi & 63) * 4;
    *(float4*)(cs + row * 260 + col) =
        *(const float4*)(cents + ((size_t)(cg * 16 + row)) * 256 + col);
  }

  float xr[2][16];
#pragma unroll
  for (int s = 0; s < 2; ++s)
#pragma unroll
    for (int qq = 0; qq < 4; ++qq) {
      float4 tv = *(const float4*)(x + (size_t)(n0 + t + 16 * s) * IN_DIM +
                                   cg * 256 + cl * 16 + qq * 4);
      xr[s][qq * 4 + 0] = tv.x; xr[s][qq * 4 + 1] = tv.y;
      xr[s][qq * 4 + 2] = tv.z; xr[s][qq * 4 + 3] = tv.w;
    }
  __syncthreads();

  const float* cb = cs + cl * 260;
  int bk0 = 0, bk1 = 0;
  float bd0 = 1e30f, bd1 = 1e30f;
#pragma unroll
  for (int k = 0; k < 16; ++k) {
    float d0 = 0.f, d1 = 0.f;
#pragma unroll
    for (int qq = 0; qq < 4; ++qq) {
      float4 cv = *(const float4*)(cb + k * 16 + qq * 4);
      d0 = fmaxf(d0, fabsf(xr[0][qq * 4 + 0] - cv.x));
      d0 = fmaxf(d0, fabsf(xr[0][qq * 4 + 1] - cv.y));
      d0 = fmaxf(d0, fabsf(xr[0][qq * 4 + 2] - cv.z));
      d0 = fmaxf(d0, fabsf(xr[0][qq * 4 + 3] - cv.w));
      d1 = fmaxf(d1, fabsf(xr[1][qq * 4 + 0] - cv.x));
      d1 = fmaxf(d1, fabsf(xr[1][qq * 4 + 1] - cv.y));
      d1 = fmaxf(d1, fabsf(xr[1][qq * 4 + 2] - cv.z));
      d1 = fmaxf(d1, fabsf(xr[1][qq * 4 + 3] - cv.w));
    }
    if (d0 < bd0) { bd0 = d0; bk0 = k; }
    if (d1 < bd1) { bd1 = d1; bk1 = k; }
  }
  idx[(size_t)(n0 + t) * NCB + cg * 16 + cl] = (unsigned char)bk0;
  idx[(size_t)(n0 + t + 16) * NCB + cg * 16 + cl] = (unsigned char)bk1;
}

// ---------------------------------------------------------------------------
// k_gemm v12 = R4/R11's best-measured kernel (62.5us, MfmaUtil 44%, VGPR
// 104) with ONE delta: T19 sched_group_barrier directives per j-body
// forcing a 1-MFMA : 3-VALU emitted interleave.  Mechanism: measured
// per-wave k-block period 590 cyc == MFMA pipe (310) + VALU (270) SUMMED;
// at ~1.4 resident waves/SIMD the in-order wave stalls issuing 16
// back-to-back MFMAs (pipe-queue full) and its next-build VALU cannot
// issue under the MFMA shadow.  The directives ask the scheduler to
// alternate, letting build-VALU fill MFMA pipe-drain cycles.
// Masks (LLVM SchedGroupMask): VALU=0x2, MFMA=0x8, VMEM_READ=0x20.
// ---------------------------------------------------------------------------
__global__ __launch_bounds__(256) void k_gemm(
    const unsigned char* __restrict__ idx,  // [N_TOK][NCB] u8
    const char* __restrict__ Bf,            // fragment-ordered LUT
    const float* __restrict__ bias,
    float* __restrict__ out) {
  __shared__ unsigned char sIdx[128 * 144];  // 18KB, 16B-aligned rows
  const int tid = threadIdx.x;
  const int wave = tid >> 6;
  const int lane = tid & 63;

  // bijective XCD swizzle over grid (32,32)
  const int lin = blockIdx.x + (int)(gridDim.x * blockIdx.y);
  const int slot = lin >> 3;
  const int bx = slot & 31;
  const int by = ((lin & 7) << 2) | (slot >> 5);
  const int m0 = bx * 128;
  const int n0 = by * 128;
  const int wm = (wave >> 1) * 64;
  const int wn = (wave & 1) * 64;

  // ---- stage sIdx (16KB payload, coalesced) ----
#pragma unroll
  for (int j = 0; j < 4; ++j) {
    const int u = tid + 256 * j;
    const int row = u >> 3;
    const int col = (u & 7) * 16;
    *(uint4*)(sIdx + row * 144 + col) =
        *(const uint4*)(idx + (size_t)(m0 + row) * NCB + col);
  }

  // lane constants for the register one-hot build (R4-verified)
  const int h = lane >> 4;
  const u32 sh_e = (u32)((h >> 1) * 8);        // even-j nibble shift
  const u32 sh_o = sh_e + 16u;                 // odd-j nibble shift
  const u32 pxor = (h & 1) ? 0x08080808u : 0u; // par8 pre-xor
  const unsigned char* rb[4];
#pragma unroll
  for (int i = 0; i < 4; ++i) rb[i] = sIdx + (wm + i * 16 + (lane & 15)) * 144;

  // B-frag rolling offsets (32-bit, SGPR-base addressing); +=1024 per k-block
  const int tb = (n0 >> 4) + (wn >> 4);
  u32 bo0 = (u32)(tb + 0) * (KB * 1024) + (u32)lane * 16;
  u32 bo1 = bo0 + KB * 1024;
  u32 bo2 = bo1 + KB * 1024;
  u32 bo3 = bo2 + KB * 1024;

  __syncthreads();  // sIdx visible -- the ONLY barrier in this kernel

  uint4 Bc0 = *(const uint4*)(Bf + bo0);
  uint4 Bc1 = *(const uint4*)(Bf + bo1);
  uint4 Bc2 = *(const uint4*)(Bf + bo2);
  uint4 Bc3 = *(const uint4*)(Bf + bo3);
  bo0 += 1024; bo1 += 1024; bo2 += 1024; bo3 += 1024;

  f32x4 acc[4][4] = {};

  for (int q = 0; q < 8; ++q) {
    // idx chunk: 16 codebooks (8 k-blocks); broadcast LDS reads, pre-XOR'd
    uint4 ch[4];
#pragma unroll
    for (int i = 0; i < 4; ++i) {
      ch[i] = *(const uint4*)(rb[i] + q * 16);
      ch[i].x ^= pxor; ch[i].y ^= pxor; ch[i].z ^= pxor; ch[i].w ^= pxor;
    }

#pragma unroll
    for (int j = 0; j < 8; ++j) {
      // prefetch next k-block's B (q=7,j=7 over-reads 1KB into the idx
      // region: allocated, values dead)
      uint4 Bn0 = *(const uint4*)(Bf + bo0);
      uint4 Bn1 = *(const uint4*)(Bf + bo1);
      uint4 Bn2 = *(const uint4*)(Bf + bo2);
      uint4 Bn3 = *(const uint4*)(Bf + bo3);
      bo0 += 1024; bo1 += 1024; bo2 += 1024; bo3 += 1024;

      // build 4 one-hot A fragments in registers (~11 VALU each, trimmed)
      const u32 sh = (j & 1) ? sh_o : sh_e;
      bf16x8 af[4];
#pragma unroll
      for (int i = 0; i < 4; ++i) {
        const u32 word = (j >> 1) == 0 ? ch[i].x
                       : (j >> 1) == 1 ? ch[i].y
                       : (j >> 1) == 2 ? ch[i].z
                                       : ch[i].w;
        const u32 uu = (word >> sh) & 15u;
        const u32 sa = (uu << 4) & 63u;
        const u64 dbl = 0x3F80ull << sa;
        const u64 lo = (uu < 4u) ? dbl : 0ull;
        const u64 hi = ((uu - 4u) < 4u) ? dbl : 0ull;  // unsigned wrap
        uint4 f;
        f.x = (u32)lo; f.y = (u32)(lo >> 32);
        f.z = (u32)hi; f.w = (u32)(hi >> 32);
        af[i] = *(bf16x8*)&f;
      }

#pragma unroll
      for (int i = 0; i < 4; ++i) {
        acc[i][0] = __builtin_amdgcn_mfma_f32_16x16x32_bf16(
            af[i], *(const bf16x8*)&Bc0, acc[i][0], 0, 0, 0);
        acc[i][1] = __builtin_amdgcn_mfma_f32_16x16x32_bf16(
            af[i], *(const bf16x8*)&Bc1, acc[i][1], 0, 0, 0);
        acc[i][2] = __builtin_amdgcn_mfma_f32_16x16x32_bf16(
            af[i], *(const bf16x8*)&Bc2, acc[i][2], 0, 0, 0);
        acc[i][3] = __builtin_amdgcn_mfma_f32_16x16x32_bf16(
            af[i], *(const bf16x8*)&Bc3, acc[i][3], 0, 0, 0);
      }

      // T19: per-j-body emitted-order directive -- hoist the 4 B loads,
      // then alternate 1 MFMA with 3 VALU so build-VALU issues in the
      // MFMA pipe shadow (in-order wave no longer stalls on the pipe).
      __builtin_amdgcn_sched_group_barrier(0x20, 4, 0);   // 4 VMEM_READ
#pragma unroll
      for (int g = 0; g < 16; ++g) {
        __builtin_amdgcn_sched_group_barrier(0x8, 1, 0);  // 1 MFMA
        __builtin_amdgcn_sched_group_barrier(0x2, 3, 0);  // 3 VALU
      }

      Bc0 = Bn0; Bc1 = Bn1; Bc2 = Bn2; Bc3 = Bn3;  // SSA-renamed by unroll
    }
  }

  // epilogue: D layout col=lane&15, row=(lane>>4)*4+r  [m89-verified]
  const int col = lane & 15;
  const int rq = (lane >> 4) * 4;
  float bj[4];
#pragma unroll
  for (int j = 0; j < 4; ++j) bj[j] = bias[n0 + wn + j * 16 + col];
#pragma unroll
  for (int i = 0; i < 4; ++i) {
    const int gm = m0 + wm + i * 16 + rq;
#pragma unroll
    for (int j = 0; j < 4; ++j) {
      const int gn = n0 + wn + j * 16 + col;
      float* op = out + (size_t)gm * OUT_DIM + gn;
#pragma unroll
      for (int r = 0; r < 4; ++r) op[(size_t)r * OUT_DIM] = acc[i][j][r] + bj[j];
    }
  }
}

// ---------------------------------------------------------------------------
extern "C" void kernel_launch(void* const* d_in, const int* in_sizes, int n_in,
                              void* d_out, int out_size, void* d_ws, size_t ws_size,
                              hipStream_t stream) {
  (void)in_sizes; (void)n_in; (void)out_size; (void)ws_size;
  const float* x      = (const float*)d_in[0];
  const float* weight = (const float*)d_in[1];
  const float* cents  = (const float*)d_in[2];
  const float* bias   = (const float*)d_in[3];
  // d_in[4] = vec_len (16), hardcoded

  char* lutF = (char*)d_ws;                                              // 16.8MB
  unsigned char* idx = (unsigned char*)d_ws + (size_t)OUT_DIM * CK * 2;  // 512KB
  float* out = (float*)d_out;

  k_prep<<<dim3(2048), 256, 0, stream>>>(x, weight, cents, idx, lutF);
  k_gemm<<<dim3(32, 32), 256, 0, stream>>>(idx, lutF, bias, out);
}

// Round 13
// 170.888 us; speedup vs baseline: 1.1959x; 1.1959x over previous
//
#include <hip/hip_runtime.h>

typedef unsigned int u32;
typedef unsigned long long u64;
typedef __bf16 bf16x8 __attribute__((ext_vector_type(8)));
typedef float f32x4 __attribute__((ext_vector_type(4)));

#define N_TOK 4096   // B*S
#define IN_DIM 2048
#define OUT_DIM 4096
#define NCB 128      // codebooks C
#define NCENT 16     // centroids K
#define VLEN 16      // vec_len V
#define CK 2048      // NCB*NCENT  (GEMM inner dim)
#define KB 64        // K-blocks (CK/32)

static __device__ __forceinline__ unsigned short f2bf(float f) {
  u32 u = __float_as_uint(f);
  u = (u + 0x7FFFu + ((u >> 16) & 1u)) >> 16;  // round-to-nearest-even
  return (unsigned short)u;
}

// ---------------------------------------------------------------------------
// k_prep: lut-build (blocks 0..1023) || Chebyshev argmin (blocks 1024..2047).
// Unchanged (passed R2-R12; not the bottleneck).
// ---------------------------------------------------------------------------
__global__ __launch_bounds__(256) void k_prep(
    const float* __restrict__ x,
    const float* __restrict__ w,
    const float* __restrict__ cents,
    unsigned char* __restrict__ idx,
    char* __restrict__ lutF) {
  __shared__ float cs[16 * 260];  // 16.6KB (argmin path only)
  const int tid = threadIdx.x;
  const int b = blockIdx.x;

  if (b < 1024) {
    // ---- LUT path ----
    const int o0 = (b & 63) * 64;
    const int cg = b >> 6;  // 8-codebook group 0..15
    const int p = tid >> 6;
    const int ol = tid & 63;
    const int o = o0 + ol;

    float acc[2][16];
#pragma unroll
    for (int cc = 0; cc < 2; ++cc)
#pragma unroll
      for (int k = 0; k < 16; ++k) acc[cc][k] = 0.f;

#pragma unroll
    for (int cc = 0; cc < 2; ++cc) {
      const int c = __builtin_amdgcn_readfirstlane(cg * 8 + p * 2 + cc);
      const float* cb = cents + (size_t)c * (NCENT * VLEN);  // scalar loads
#pragma unroll
      for (int v = 0; v < VLEN; ++v) {
        const float wv = w[(size_t)(c * 16 + v) * OUT_DIM + o];
#pragma unroll
        for (int k = 0; k < 16; ++k) acc[cc][k] = fmaf(cb[k * 16 + v], wv, acc[cc][k]);
      }
    }

#pragma unroll
    for (int cc = 0; cc < 2; ++cc) {
      const int c = cg * 8 + p * 2 + cc;
      u32 g[8];
#pragma unroll
      for (int kk = 0; kk < 8; ++kk)
        g[kk] = (u32)f2bf(acc[cc][2 * kk]) | ((u32)f2bf(acc[cc][2 * kk + 1]) << 16);
      char* base = lutF + ((size_t)(o >> 4) * KB + (c >> 1)) * 1024;
      const int l0 = (o & 15) + ((c & 1) * 2) * 16;
      *(uint4*)(base + l0 * 16)        = make_uint4(g[0], g[1], g[2], g[3]);
      *(uint4*)(base + (l0 + 16) * 16) = make_uint4(g[4], g[5], g[6], g[7]);
    }
    return;
  }

  // ---- argmin path ----
  const int a = b - 1024;
  const int n0 = (a & 127) * 32;
  const int cg = a >> 7;  // column chunk 0..7
  const int t = tid >> 4;
  const int cl = tid & 15;

#pragma unroll
  for (int j2 = 0; j2 < 4; ++j2) {
    const int fi = tid + 256 * j2;
    const int row = fi >> 6;
    const int col = (fi & 63) * 4;
    *(float4*)(cs + row * 260 + col) =
        *(const float4*)(cents + ((size_t)(cg * 16 + row)) * 256 + col);
  }

  float xr[2][16];
#pragma unroll
  for (int s = 0; s < 2; ++s)
#pragma unroll
    for (int qq = 0; qq < 4; ++qq) {
      float4 tv = *(const float4*)(x + (size_t)(n0 + t + 16 * s) * IN_DIM +
                                   cg * 256 + cl * 16 + qq * 4);
      xr[s][qq * 4 + 0] = tv.x; xr[s][qq * 4 + 1] = tv.y;
      xr[s][qq * 4 + 2] = tv.z; xr[s][qq * 4 + 3] = tv.w;
    }
  __syncthreads();

  const float* cb = cs + cl * 260;
  int bk0 = 0, bk1 = 0;
  float bd0 = 1e30f, bd1 = 1e30f;
#pragma unroll
  for (int k = 0; k < 16; ++k) {
    float d0 = 0.f, d1 = 0.f;
#pragma unroll
    for (int qq = 0; qq < 4; ++qq) {
      float4 cv = *(const float4*)(cb + k * 16 + qq * 4);
      d0 = fmaxf(d0, fabsf(xr[0][qq * 4 + 0] - cv.x));
      d0 = fmaxf(d0, fabsf(xr[0][qq * 4 + 1] - cv.y));
      d0 = fmaxf(d0, fabsf(xr[0][qq * 4 + 2] - cv.z));
      d0 = fmaxf(d0, fabsf(xr[0][qq * 4 + 3] - cv.w));
      d1 = fmaxf(d1, fabsf(xr[1][qq * 4 + 0] - cv.x));
      d1 = fmaxf(d1, fabsf(xr[1][qq * 4 + 1] - cv.y));
      d1 = fmaxf(d1, fabsf(xr[1][qq * 4 + 2] - cv.z));
      d1 = fmaxf(d1, fabsf(xr[1][qq * 4 + 3] - cv.w));
    }
    if (d0 < bd0) { bd0 = d0; bk0 = k; }
    if (d1 < bd1) { bd1 = d1; bk1 = k; }
  }
  idx[(size_t)(n0 + t) * NCB + cg * 16 + cl] = (unsigned char)bk0;
  idx[(size_t)(n0 + t + 16) * NCB + cg * 16 + cl] = (unsigned char)bk1;
}

// ---------------------------------------------------------------------------
// k_gemm = the twice-reproduced best configuration (R4=62.9us, R11=62.5us;
// MfmaUtil 44%, VALU 47%, VGPR 104, conflicts 0).  Full perturbation ledger:
// v6 LDS-table 66.9 / v7 128x32 83.4 / v8 dist-2 68.5 / v9 setprio 64.5 /
// v10 32x128 99.0 / v12 sched_group_barrier 92.8 -- every within-family
// lever measured worse or null.  hipcc's natural schedule of this shape is
// the local optimum: ~85-90% of the matrix throughput available at its
// achieved occupancy (~1.4 waves/SIMD; per-wave period 590cyc ~= MFMA 310 +
// VALU 270 summed, in-order issue).  Further gains need a different kernel
// family (32x32x16 MFMA + re-laid-out LUT + 2-block/CU schedule).
// ---------------------------------------------------------------------------
__global__ __launch_bounds__(256) void k_gemm(
    const unsigned char* __restrict__ idx,  // [N_TOK][NCB] u8
    const char* __restrict__ Bf,            // fragment-ordered LUT
    const float* __restrict__ bias,
    float* __restrict__ out) {
  __shared__ unsigned char sIdx[128 * 144];  // 18KB, 16B-aligned rows
  const int tid = threadIdx.x;
  const int wave = tid >> 6;
  const int lane = tid & 63;

  // bijective XCD swizzle over grid (32,32)
  const int lin = blockIdx.x + (int)(gridDim.x * blockIdx.y);
  const int slot = lin >> 3;
  const int bx = slot & 31;
  const int by = ((lin & 7) << 2) | (slot >> 5);
  const int m0 = bx * 128;
  const int n0 = by * 128;
  const int wm = (wave >> 1) * 64;
  const int wn = (wave & 1) * 64;

  // ---- stage sIdx (16KB payload, coalesced) ----
#pragma unroll
  for (int j = 0; j < 4; ++j) {
    const int u = tid + 256 * j;
    const int row = u >> 3;
    const int col = (u & 7) * 16;
    *(uint4*)(sIdx + row * 144 + col) =
        *(const uint4*)(idx + (size_t)(m0 + row) * NCB + col);
  }

  // lane constants for the register one-hot build (R4-verified)
  const int h = lane >> 4;
  const u32 sh_e = (u32)((h >> 1) * 8);        // even-j nibble shift
  const u32 sh_o = sh_e + 16u;                 // odd-j nibble shift
  const u32 pxor = (h & 1) ? 0x08080808u : 0u; // par8 pre-xor
  const unsigned char* rb[4];
#pragma unroll
  for (int i = 0; i < 4; ++i) rb[i] = sIdx + (wm + i * 16 + (lane & 15)) * 144;

  // B-frag rolling offsets (32-bit, SGPR-base addressing); +=1024 per k-block
  const int tb = (n0 >> 4) + (wn >> 4);
  u32 bo0 = (u32)(tb + 0) * (KB * 1024) + (u32)lane * 16;
  u32 bo1 = bo0 + KB * 1024;
  u32 bo2 = bo1 + KB * 1024;
  u32 bo3 = bo2 + KB * 1024;

  __syncthreads();  // sIdx visible -- the ONLY barrier in this kernel

  uint4 Bc0 = *(const uint4*)(Bf + bo0);
  uint4 Bc1 = *(const uint4*)(Bf + bo1);
  uint4 Bc2 = *(const uint4*)(Bf + bo2);
  uint4 Bc3 = *(const uint4*)(Bf + bo3);
  bo0 += 1024; bo1 += 1024; bo2 += 1024; bo3 += 1024;

  f32x4 acc[4][4] = {};

  for (int q = 0; q < 8; ++q) {
    // idx chunk: 16 codebooks (8 k-blocks); broadcast LDS reads, pre-XOR'd
    uint4 ch[4];
#pragma unroll
    for (int i = 0; i < 4; ++i) {
      ch[i] = *(const uint4*)(rb[i] + q * 16);
      ch[i].x ^= pxor; ch[i].y ^= pxor; ch[i].z ^= pxor; ch[i].w ^= pxor;
    }

#pragma unroll
    for (int j = 0; j < 8; ++j) {
      // prefetch next k-block's B (q=7,j=7 over-reads 1KB into the idx
      // region: allocated, values dead)
      uint4 Bn0 = *(const uint4*)(Bf + bo0);
      uint4 Bn1 = *(const uint4*)(Bf + bo1);
      uint4 Bn2 = *(const uint4*)(Bf + bo2);
      uint4 Bn3 = *(const uint4*)(Bf + bo3);
      bo0 += 1024; bo1 += 1024; bo2 += 1024; bo3 += 1024;

      // build 4 one-hot A fragments in registers (~11 VALU each, trimmed)
      const u32 sh = (j & 1) ? sh_o : sh_e;
      bf16x8 af[4];
#pragma unroll
      for (int i = 0; i < 4; ++i) {
        const u32 word = (j >> 1) == 0 ? ch[i].x
                       : (j >> 1) == 1 ? ch[i].y
                       : (j >> 1) == 2 ? ch[i].z
                                       : ch[i].w;
        const u32 uu = (word >> sh) & 15u;
        const u32 sa = (uu << 4) & 63u;
        const u64 dbl = 0x3F80ull << sa;
        const u64 lo = (uu < 4u) ? dbl : 0ull;
        const u64 hi = ((uu - 4u) < 4u) ? dbl : 0ull;  // unsigned wrap
        uint4 f;
        f.x = (u32)lo; f.y = (u32)(lo >> 32);
        f.z = (u32)hi; f.w = (u32)(hi >> 32);
        af[i] = *(bf16x8*)&f;
      }

#pragma unroll
      for (int i = 0; i < 4; ++i) {
        acc[i][0] = __builtin_amdgcn_mfma_f32_16x16x32_bf16(
            af[i], *(const bf16x8*)&Bc0, acc[i][0], 0, 0, 0);
        acc[i][1] = __builtin_amdgcn_mfma_f32_16x16x32_bf16(
            af[i], *(const bf16x8*)&Bc1, acc[i][1], 0, 0, 0);
        acc[i][2] = __builtin_amdgcn_mfma_f32_16x16x32_bf16(
            af[i], *(const bf16x8*)&Bc2, acc[i][2], 0, 0, 0);
        acc[i][3] = __builtin_amdgcn_mfma_f32_16x16x32_bf16(
            af[i], *(const bf16x8*)&Bc3, acc[i][3], 0, 0, 0);
      }

      Bc0 = Bn0; Bc1 = Bn1; Bc2 = Bn2; Bc3 = Bn3;  // SSA-renamed by unroll
    }
  }

  // epilogue: D layout col=lane&15, row=(lane>>4)*4+r  [m89-verified]
  const int col = lane & 15;
  const int rq = (lane >> 4) * 4;
  float bj[4];
#pragma unroll
  for (int j = 0; j < 4; ++j) bj[j] = bias[n0 + wn + j * 16 + col];
#pragma unroll
  for (int i = 0; i < 4; ++i) {
    const int gm = m0 + wm + i * 16 + rq;
#pragma unroll
    for (int j = 0; j < 4; ++j) {
      const int gn = n0 + wn + j * 16 + col;
      float* op = out + (size_t)gm * OUT_DIM + gn;
#pragma unroll
      for (int r = 0; r < 4; ++r) op[(size_t)r * OUT_DIM] = acc[i][j][r] + bj[j];
    }
  }
}

// ---------------------------------------------------------------------------
extern "C" void kernel_launch(void* const* d_in, const int* in_sizes, int n_in,
                              void* d_out, int out_size, void* d_ws, size_t ws_size,
                              hipStream_t stream) {
  (void)in_sizes; (void)n_in; (void)out_size; (void)ws_size;
  const float* x      = (const float*)d_in[0];
  const float* weight = (const float*)d_in[1];
  const float* cents  = (const float*)d_in[2];
  const float* bias   = (const float*)d_in[3];
  // d_in[4] = vec_len (16), hardcoded

  char* lutF = (char*)d_ws;                                              // 16.8MB
  unsigned char* idx = (unsigned char*)d_ws + (size_t)OUT_DIM * CK * 2;  // 512KB
  float* out = (float*)d_out;

  k_prep<<<dim3(2048), 256, 0, stream>>>(x, weight, cents, idx, lutF);
  k_gemm<<<dim3(32, 32), 256, 0, stream>>>(idx, lutF, bias, out);
}